// Round 6
// baseline (14872.806 us; speedup 1.0000x reference)
//
#include <hip/hip_runtime.h>
#include <math.h>

#define D_IN    1024
#define D_CELL  2048
#define T_STEPS 2048
#define D_Z     3072            // D_IN + D_CELL
#define R_TOTAL (4 * D_CELL)    // 8192 gate rows
#define NBLK    256
#define NTHR    1024

typedef unsigned long long u64;

// ---------------------------------------------------------------------------
// init: zero the h-exchange slots (harness does NOT re-poison ws between
// timed replays; stale tags from a previous replay would satisfy polls).
// slots = u64[2][D_CELL] PACKED (round-5 lesson: poll cost scales with the
// polled footprint — spreading slots across private lines made it 2x WORSE;
// keep the whole array at 32 KB).
// ---------------------------------------------------------------------------
__global__ void lstm_init_kernel(u64* __restrict__ slots) {
    int i = blockIdx.x * 256 + threadIdx.x;
    if (i < 2 * D_CELL) slots[i] = 0ull;
}

// ---------------------------------------------------------------------------
// Gx[r][t] = b[r] + sum_k W_g[d][k] * x[k][t]   (k < 1024, input part)
// 1D grid of 2048 blocks, XCD-aware decode: each XCD works on ONE t-half
// (same 4 MiB x tile -> fits its private 4 MiB L2). 256 threads, each
// handles 4 t-columns x 8 rows. W row loads are wave-uniform -> s_load.
// ---------------------------------------------------------------------------
__global__ __launch_bounds__(256) void lstm_gx_kernel(
    const float* __restrict__ Wf, const float* __restrict__ bf,
    const float* __restrict__ Wi, const float* __restrict__ bi,
    const float* __restrict__ Wc, const float* __restrict__ bc,
    const float* __restrict__ Wo, const float* __restrict__ bo,
    const float* __restrict__ x,  float* __restrict__ Gx)
{
    const int bid = blockIdx.x;          // 0..2047
    const int xcd = bid & 7;             // HW round-robin: bid%8 = XCD
    const int loc = bid >> 3;            // 0..255
    const int tx  = xcd >> 2;            // t-half 0/1 (4 XCDs per half)
    const int yb  = (xcd & 3) * 256 + loc;   // row-block 0..1023
    const int tid = threadIdx.x;
    const int t0  = tx * 1024 + tid * 4;
    const int r0  = yb * 8;
    const int g   = r0 >> 11;
    const int d0  = r0 & 2047;
    const float* W = (g == 0) ? Wf : (g == 1) ? Wi : (g == 2) ? Wc : Wo;
    const float* b = (g == 0) ? bf : (g == 1) ? bi : (g == 2) ? bc : bo;

    const float* wr0 = W + (size_t)(d0 + 0) * D_Z;
    const float* wr1 = W + (size_t)(d0 + 1) * D_Z;
    const float* wr2 = W + (size_t)(d0 + 2) * D_Z;
    const float* wr3 = W + (size_t)(d0 + 3) * D_Z;
    const float* wr4 = W + (size_t)(d0 + 4) * D_Z;
    const float* wr5 = W + (size_t)(d0 + 5) * D_Z;
    const float* wr6 = W + (size_t)(d0 + 6) * D_Z;
    const float* wr7 = W + (size_t)(d0 + 7) * D_Z;

    float4 acc[8];
#pragma unroll
    for (int jr = 0; jr < 8; ++jr) acc[jr] = make_float4(0.f, 0.f, 0.f, 0.f);

    for (int k = 0; k < D_IN; k += 4) {
        float4 xa = *(const float4*)(x + (size_t)(k + 0) * T_STEPS + t0);
        float4 xb = *(const float4*)(x + (size_t)(k + 1) * T_STEPS + t0);
        float4 xc = *(const float4*)(x + (size_t)(k + 2) * T_STEPS + t0);
        float4 xd = *(const float4*)(x + (size_t)(k + 3) * T_STEPS + t0);
        const float* wrs[8] = {wr0, wr1, wr2, wr3, wr4, wr5, wr6, wr7};
#pragma unroll
        for (int jr = 0; jr < 8; ++jr) {
            float4 w = *(const float4*)(wrs[jr] + k);   // wave-uniform
            acc[jr].x += w.x * xa.x + w.y * xb.x + w.z * xc.x + w.w * xd.x;
            acc[jr].y += w.x * xa.y + w.y * xb.y + w.z * xc.y + w.w * xd.y;
            acc[jr].z += w.x * xa.z + w.y * xb.z + w.z * xc.z + w.w * xd.z;
            acc[jr].w += w.x * xa.w + w.y * xb.w + w.z * xc.w + w.w * xd.w;
        }
    }

#pragma unroll
    for (int jr = 0; jr < 8; ++jr) {
        float bb = b[d0 + jr];
        float4 o = acc[jr];
        o.x += bb; o.y += bb; o.z += bb; o.w += bb;
        *(float4*)(Gx + (size_t)(r0 + jr) * T_STEPS + t0) = o;
    }
}

// ---------------------------------------------------------------------------
// Persistent recurrence kernel — round-3 skeleton (256 blocks, 16 waves,
// 2 rows/wave, packed slots, weight loads before the loop; compiler keeps the
// 64 floats/lane on-chip in AGPRs — do NOT add register-class asm, round 2
// showed "+v" forces scratch spills). ONE structural change vs round 3:
// pair-handoff tail replaces {sync B + single-wave 8-cell activation}.
//   Wave pair (2c,2c+1) owns cell c. Odd wave (gates cand,o) posts its two
//   row-sums to tagged LDS slots after its butterfly and falls straight into
//   the t+1 poll. Even wave (gates f,i in-register) spins on the two LDS
//   slots (s_sleep backoff — round-4's hot spin is the suspected livelock),
//   computes the activation redundantly on all lanes, lane 0 publishes
//   immediately. Publish of cell c is gated on its own pair only.
// hs is double-buffered (required without sync B). Safety: stage(t+2) into
// hs[par] happens after sync A(t+1), which orders it after every wave's
// dot(t) reads of hs[par]; gslot(t) is consumed before sync A(t+1) can pass.
// ---------------------------------------------------------------------------
__global__ __launch_bounds__(NTHR, 4) void lstm_rec_kernel(
    const float* __restrict__ Wf, const float* __restrict__ Wi,
    const float* __restrict__ Wc, const float* __restrict__ Wo,
    const float* __restrict__ Gx, u64* __restrict__ slots,
    float* __restrict__ out)
{
    __shared__ float hs[2][D_CELL];  // h_{t-1}, double-buffered
    __shared__ u64   gslot[16];      // tagged (cand,o) sums: cell cp -> 2cp,2cp+1

    const int tid  = threadIdx.x;
    const int w    = tid >> 6;       // wave 0..15
    const int lane = tid & 63;
    const int r0   = 2 * w;          // rows r0, r0+1  (row = cell*4 + gate)
    const int cp   = w >> 1;         // owned cell 0..7 (pair of waves 2cp,2cp+1)

    // ---- load my two weight rows (fp32, stay on-chip in VGPRs/AGPRs) ----
    const int g0 = r0 & 3,        g1 = (r0 + 1) & 3;
    const int d  = blockIdx.x * 8 + cp;           // global cell
    const float* Wb0 = ((g0 == 0) ? Wf : (g0 == 1) ? Wi : (g0 == 2) ? Wc : Wo)
                       + (size_t)d * D_Z + D_IN;
    const float* Wb1 = ((g1 == 0) ? Wf : (g1 == 1) ? Wi : (g1 == 2) ? Wc : Wo)
                       + (size_t)d * D_Z + D_IN;
    float4 wA[8], wB[8];
#pragma unroll
    for (int j = 0; j < 8; ++j) {
        wA[j] = *(const float4*)(Wb0 + j * 256 + lane * 4);
        wB[j] = *(const float4*)(Wb1 + j * 256 + lane * 4);
    }

    // Gx row base for lanes 0,1 (lane L handles row r0+L)
    const int myrow = r0 + (lane & 1);
    const size_t gxbase = (size_t)((myrow & 3) * D_CELL
                                   + blockIdx.x * 8 + (myrow >> 2)) * T_STEPS;

    if (tid < 16) gslot[tid] = 0ull;   // ordered before first use by sync A(0)

    float cst = 0.f;                 // cell state (even waves, lane-redundant)
    const float L2E  = 1.442695041f;     // log2(e)
    const float L2E2 = 2.885390082f;     // 2*log2(e)

    for (int t = 0; t < T_STEPS; ++t) {
        // prefetch Gx early (independent of poll)
        float gx_pref = 0.f;
        if (lane < 2) gx_pref = Gx[gxbase + t];

        const int par = t & 1;
        // ---- acquire h_{t-1}: batched poll of my 2 packed slots ----
        if (t == 0) {
            hs[0][2 * tid]     = 0.f;
            hs[0][2 * tid + 1] = 0.f;
        } else {
            const u64* bp = slots + (size_t)par * D_CELL + 2 * tid;
            const u64 tg = (u64)(unsigned)t << 32;
            u64 a, b;
            for (;;) {
                a = __hip_atomic_load(bp + 0, __ATOMIC_RELAXED,
                                      __HIP_MEMORY_SCOPE_AGENT);
                b = __hip_atomic_load(bp + 1, __ATOMIC_RELAXED,
                                      __HIP_MEMORY_SCOPE_AGENT);
                if ((((a ^ tg) | (b ^ tg)) >> 32) == 0) break;
                __builtin_amdgcn_s_sleep(1);
            }
            hs[par][2 * tid]     = __uint_as_float((unsigned)a);
            hs[par][2 * tid + 1] = __uint_as_float((unsigned)b);
        }
        __syncthreads();                          // sync A: hs[par] ready

        // ---- two gate-row dot slices from on-chip weights ----
        float acc0 = 0.f, acc1 = 0.f;
#pragma unroll
        for (int j = 0; j < 8; ++j) {
            float4 h = *(const float4*)&hs[par][j * 256 + lane * 4];
            acc0 += wA[j].x * h.x + wA[j].y * h.y + wA[j].z * h.z + wA[j].w * h.w;
            acc1 += wB[j].x * h.x + wB[j].y * h.y + wB[j].z * h.z + wB[j].w * h.w;
        }
        // paired butterfly: even lanes -> row r0 sum, odd lanes -> row r0+1
        float vK = (lane & 1) ? acc1 : acc0;
        float vO = (lane & 1) ? acc0 : acc1;
        float v  = vK + __shfl_xor(vO, 1);
        v += __shfl_xor(v, 2);
        v += __shfl_xor(v, 4);
        v += __shfl_xor(v, 8);
        v += __shfl_xor(v, 16);
        v += __shfl_xor(v, 32);

        if (w & 1) {
            // ---- odd wave (gates cand,o): post sums, fall into next poll ----
            if (lane < 2) {
                u64 pk = ((u64)(unsigned)(t + 1) << 32)
                       | (u64)__float_as_uint(v + gx_pref);
                __hip_atomic_store(&gslot[2 * cp + lane], pk,
                                   __ATOMIC_RELAXED,
                                   __HIP_MEMORY_SCOPE_WORKGROUP);
            }
        } else {
            // ---- even wave (gates f,i): all-lane gf,gi; spin for cand,o ----
            float vs  = __shfl_xor(v, 1);
            float gxA = __shfl(gx_pref, 0);
            float gxB = __shfl(gx_pref, 1);
            float gf = ((lane & 1) ? vs : v) + gxA;
            float gi = ((lane & 1) ? v : vs) + gxB;

            const u64 tgl = (u64)(unsigned)(t + 1) << 32;
            u64 s2, s3;
            for (;;) {
                s2 = __hip_atomic_load(&gslot[2 * cp + 0], __ATOMIC_RELAXED,
                                       __HIP_MEMORY_SCOPE_WORKGROUP);
                s3 = __hip_atomic_load(&gslot[2 * cp + 1], __ATOMIC_RELAXED,
                                       __HIP_MEMORY_SCOPE_WORKGROUP);
                if ((((s2 ^ tgl) | (s3 ^ tgl)) >> 32) == 0) break;
                __builtin_amdgcn_s_sleep(1);      // round-4 lesson: no hot spin
            }
            float gc = __uint_as_float((unsigned)s2);
            float go = __uint_as_float((unsigned)s3);

            // fast activations (validated: identical absmax since round 1)
            float f    = __builtin_amdgcn_rcpf(
                             1.f + __builtin_amdgcn_exp2f(-L2E * gf));
            float ig   = __builtin_amdgcn_rcpf(
                             1.f + __builtin_amdgcn_exp2f(-L2E * gi));
            float o    = __builtin_amdgcn_rcpf(
                             1.f + __builtin_amdgcn_exp2f(-L2E * go));
            float cand = 1.f - 2.f * __builtin_amdgcn_rcpf(
                             __builtin_amdgcn_exp2f(L2E2 * gc) + 1.f);
            cst = f * cst + ig * cand;
            float tc   = 1.f - 2.f * __builtin_amdgcn_rcpf(
                             __builtin_amdgcn_exp2f(L2E2 * cst) + 1.f);
            float hn = o * tc;

            if (lane == 0) {
                if (t + 1 < T_STEPS) {            // publish FIRST
                    u64 pk = ((u64)(unsigned)(t + 1) << 32)
                           | (u64)__float_as_uint(hn);
                    __hip_atomic_store(
                        slots + (size_t)((t + 1) & 1) * D_CELL + d,
                        pk, __ATOMIC_RELAXED, __HIP_MEMORY_SCOPE_AGENT);
                }
                out[(size_t)d * T_STEPS + t] = hn;
            }
        }
    }
}

// ---------------------------------------------------------------------------
extern "C" void kernel_launch(void* const* d_in, const int* in_sizes, int n_in,
                              void* d_out, int out_size, void* d_ws, size_t ws_size,
                              hipStream_t stream) {
    const float* x  = (const float*)d_in[0];
    const float* Wf = (const float*)d_in[1];
    const float* bf = (const float*)d_in[2];
    const float* Wi = (const float*)d_in[3];
    const float* bi = (const float*)d_in[4];
    const float* Wc = (const float*)d_in[5];
    const float* bc = (const float*)d_in[6];
    const float* Wo = (const float*)d_in[7];
    const float* bo = (const float*)d_in[8];
    float* out = (float*)d_out;

    // ws layout: Gx fp32 [8192][2048] | slots u64 [2][2048] (packed)
    const size_t gx_elems = (size_t)R_TOTAL * T_STEPS;
    const size_t need = gx_elems * 4 + 2 * D_CELL * 8;
    if (ws_size < need) return;
    float* Gx    = (float*)d_ws;
    u64*   slots = (u64*)(Gx + gx_elems);

    lstm_init_kernel<<<16, 256, 0, stream>>>(slots);

    lstm_gx_kernel<<<2048, 256, 0, stream>>>(Wf, bf, Wi, bi, Wc, bc, Wo, bo,
                                             x, Gx);

    lstm_rec_kernel<<<NBLK, NTHR, 0, stream>>>(Wf, Wi, Wc, Wo, Gx, slots, out);
}

// Round 7
// 5840.179 us; speedup vs baseline: 2.5466x; 2.5466x over previous
//
#include <hip/hip_runtime.h>
#include <math.h>

#define D_IN    1024
#define D_CELL  2048
#define T_STEPS 2048
#define D_Z     3072            // D_IN + D_CELL
#define R_TOTAL (4 * D_CELL)    // 8192 gate rows
#define NBLK    256
#define NTHR    1024

typedef unsigned long long u64;

// ---------------------------------------------------------------------------
// Slot encoding (round-7): ONE u64 per CELL PAIR, packed:
//   [63:48] tag (= step t whose h this is; t<2048 fits 16 bits, 0 = invalid)
//   [47:24] fp32 bits of h_even, RN-truncated to 24 bits (sign+exp+15 mant)
//   [23: 0] fp32 bits of h_odd,  RN-truncated to 24 bits
// Rel. error <= 2^-16 — negligible vs measured 2e-3 absmax; `out` is exact.
// Rationale (rounds 3-6): agent-scope poll loads bypass XCD L2 -> every
// failed sweep is LLC traffic proportional to sectors swept. Pair-packing
// halves the polled footprint (16->8 KB/parity) AND makes the poll a single
// load. Do NOT: unpack slots across lines (r5: 2x worse), start polls before
// the local tail (r4/r6: 2.3-5x worse), or add register-class asm (r2).
// ---------------------------------------------------------------------------
#define SLOT_PAIRS (D_CELL / 2)          // 1024 pair-slots per parity

// init: zero the pair slots (harness does NOT re-poison ws between timed
// replays; stale tag 2047 from a previous replay would satisfy the t=2047
// poll). 2 parities x 1024 u64 = 16 KB.
__global__ void lstm_init_kernel(u64* __restrict__ slots) {
    int i = blockIdx.x * 256 + threadIdx.x;
    if (i < 2 * SLOT_PAIRS) slots[i] = 0ull;
}

// ---------------------------------------------------------------------------
// Gx[r][t] = b[r] + sum_k W_g[d][k] * x[k][t]   (k < 1024, input part)
// 1D grid of 2048 blocks, XCD-aware decode: each XCD works on ONE t-half
// (same 4 MiB x tile -> fits its private 4 MiB L2). 256 threads, each
// handles 4 t-columns x 8 rows. W row loads are wave-uniform -> s_load.
// ---------------------------------------------------------------------------
__global__ __launch_bounds__(256) void lstm_gx_kernel(
    const float* __restrict__ Wf, const float* __restrict__ bf,
    const float* __restrict__ Wi, const float* __restrict__ bi,
    const float* __restrict__ Wc, const float* __restrict__ bc,
    const float* __restrict__ Wo, const float* __restrict__ bo,
    const float* __restrict__ x,  float* __restrict__ Gx)
{
    const int bid = blockIdx.x;          // 0..2047
    const int xcd = bid & 7;             // HW round-robin: bid%8 = XCD
    const int loc = bid >> 3;            // 0..255
    const int tx  = xcd >> 2;            // t-half 0/1 (4 XCDs per half)
    const int yb  = (xcd & 3) * 256 + loc;   // row-block 0..1023
    const int tid = threadIdx.x;
    const int t0  = tx * 1024 + tid * 4;
    const int r0  = yb * 8;
    const int g   = r0 >> 11;
    const int d0  = r0 & 2047;
    const float* W = (g == 0) ? Wf : (g == 1) ? Wi : (g == 2) ? Wc : Wo;
    const float* b = (g == 0) ? bf : (g == 1) ? bi : (g == 2) ? bc : bo;

    const float* wr0 = W + (size_t)(d0 + 0) * D_Z;
    const float* wr1 = W + (size_t)(d0 + 1) * D_Z;
    const float* wr2 = W + (size_t)(d0 + 2) * D_Z;
    const float* wr3 = W + (size_t)(d0 + 3) * D_Z;
    const float* wr4 = W + (size_t)(d0 + 4) * D_Z;
    const float* wr5 = W + (size_t)(d0 + 5) * D_Z;
    const float* wr6 = W + (size_t)(d0 + 6) * D_Z;
    const float* wr7 = W + (size_t)(d0 + 7) * D_Z;

    float4 acc[8];
#pragma unroll
    for (int jr = 0; jr < 8; ++jr) acc[jr] = make_float4(0.f, 0.f, 0.f, 0.f);

    for (int k = 0; k < D_IN; k += 4) {
        float4 xa = *(const float4*)(x + (size_t)(k + 0) * T_STEPS + t0);
        float4 xb = *(const float4*)(x + (size_t)(k + 1) * T_STEPS + t0);
        float4 xc = *(const float4*)(x + (size_t)(k + 2) * T_STEPS + t0);
        float4 xd = *(const float4*)(x + (size_t)(k + 3) * T_STEPS + t0);
        const float* wrs[8] = {wr0, wr1, wr2, wr3, wr4, wr5, wr6, wr7};
#pragma unroll
        for (int jr = 0; jr < 8; ++jr) {
            float4 w = *(const float4*)(wrs[jr] + k);   // wave-uniform
            acc[jr].x += w.x * xa.x + w.y * xb.x + w.z * xc.x + w.w * xd.x;
            acc[jr].y += w.x * xa.y + w.y * xb.y + w.z * xc.y + w.w * xd.y;
            acc[jr].z += w.x * xa.z + w.y * xb.z + w.z * xc.z + w.w * xd.z;
            acc[jr].w += w.x * xa.w + w.y * xb.w + w.z * xc.w + w.w * xd.w;
        }
    }

#pragma unroll
    for (int jr = 0; jr < 8; ++jr) {
        float bb = b[d0 + jr];
        float4 o = acc[jr];
        o.x += bb; o.y += bb; o.z += bb; o.w += bb;
        *(float4*)(Gx + (size_t)(r0 + jr) * T_STEPS + t0) = o;
    }
}

// ---------------------------------------------------------------------------
// Persistent recurrence kernel — round-3 skeleton UNCHANGED (256 blocks,
// 16 waves, 2 rows/wave, weight loads before the loop; compiler keeps the
// 64 floats/lane on-chip in AGPRs — do NOT add register-class asm, round 2
// showed "+v" forces scratch spills; keep sync A + sync B + tid<8 tail —
// rounds 4/6 showed early polling floods the fabric). ONLY change vs round 3:
// packed pair slots (one u64 poll per thread, 24-bit h encoding).
// ---------------------------------------------------------------------------
__global__ __launch_bounds__(NTHR, 4) void lstm_rec_kernel(
    const float* __restrict__ Wf, const float* __restrict__ Wi,
    const float* __restrict__ Wc, const float* __restrict__ Wo,
    const float* __restrict__ Gx, u64* __restrict__ slots,
    float* __restrict__ out)
{
    __shared__ float hs[D_CELL];     // h_{t-1}, fp32
    __shared__ float gdot[32];       // per-row reduced dots

    const int tid  = threadIdx.x;
    const int w    = tid >> 6;       // wave 0..15
    const int lane = tid & 63;
    const int r0   = 2 * w;          // rows r0, r0+1  (row = cell*4 + gate)

    // ---- load my two weight rows (fp32, stay on-chip in VGPRs/AGPRs) ----
    const int g0 = r0 & 3,        g1 = (r0 + 1) & 3;
    const int cl = r0 >> 2;                       // same cell for both rows
    const int d  = blockIdx.x * 8 + cl;           // global cell
    const float* Wb0 = ((g0 == 0) ? Wf : (g0 == 1) ? Wi : (g0 == 2) ? Wc : Wo)
                       + (size_t)d * D_Z + D_IN;
    const float* Wb1 = ((g1 == 0) ? Wf : (g1 == 1) ? Wi : (g1 == 2) ? Wc : Wo)
                       + (size_t)d * D_Z + D_IN;
    float4 wA[8], wB[8];
#pragma unroll
    for (int j = 0; j < 8; ++j) {
        wA[j] = *(const float4*)(Wb0 + j * 256 + lane * 4);
        wB[j] = *(const float4*)(Wb1 + j * 256 + lane * 4);
    }

    // Gx row base for lanes 0,1 (lane L handles row r0+L)
    const int myrow = r0 + (lane & 1);
    const size_t gxbase = (size_t)((myrow & 3) * D_CELL
                                   + blockIdx.x * 8 + (myrow >> 2)) * T_STEPS;

    float c = 0.f;                   // cell state (tid<8 threads own cell tid)
    const float L2E  = 1.442695041f;     // log2(e)
    const float L2E2 = 2.885390082f;     // 2*log2(e)

    for (int t = 0; t < T_STEPS; ++t) {
        // prefetch Gx early (independent of poll)
        float gx_pref = 0.f;
        if (lane < 2) gx_pref = Gx[gxbase + t];

        // ---- acquire h_{t-1}: ONE packed pair-slot poll per thread ----
        if (t == 0) {
            hs[2 * tid]     = 0.f;
            hs[2 * tid + 1] = 0.f;
        } else {
            const u64* bp = slots + ((size_t)(t & 1) << 10) + tid;  // pair tid
            const u64 tg = (u64)(unsigned)t << 48;
            u64 s;
            for (;;) {
                s = __hip_atomic_load(bp, __ATOMIC_RELAXED,
                                      __HIP_MEMORY_SCOPE_AGENT);
                if (((s ^ tg) >> 48) == 0) break;
                __builtin_amdgcn_s_sleep(1);
            }
            hs[2 * tid]     = __uint_as_float((unsigned)(s >> 24) << 8);
            hs[2 * tid + 1] = __uint_as_float((unsigned)s << 8);
        }
        __syncthreads();                          // sync A: hs ready

        // ---- two gate-row dot slices from on-chip weights ----
        float acc0 = 0.f, acc1 = 0.f;
#pragma unroll
        for (int j = 0; j < 8; ++j) {
            float4 h = *(const float4*)(hs + j * 256 + lane * 4);
            acc0 += wA[j].x * h.x + wA[j].y * h.y + wA[j].z * h.z + wA[j].w * h.w;
            acc1 += wB[j].x * h.x + wB[j].y * h.y + wB[j].z * h.z + wB[j].w * h.w;
        }
        // paired butterfly: even lanes -> row r0 sum, odd lanes -> row r0+1
        float vK = (lane & 1) ? acc1 : acc0;
        float vO = (lane & 1) ? acc0 : acc1;
        float v  = vK + __shfl_xor(vO, 1);
        v += __shfl_xor(v, 2);
        v += __shfl_xor(v, 4);
        v += __shfl_xor(v, 8);
        v += __shfl_xor(v, 16);
        v += __shfl_xor(v, 32);
        if (lane < 2) gdot[r0 + lane] = v + gx_pref;
        __syncthreads();                          // sync B: gdot ready

        // ---- activations: one thread per owned cell (fast exp2/rcp) ----
        if (tid < 8) {
            float gf = gdot[tid * 4 + 0], gi = gdot[tid * 4 + 1];
            float gc = gdot[tid * 4 + 2], go = gdot[tid * 4 + 3];
            float f    = __builtin_amdgcn_rcpf(
                             1.f + __builtin_amdgcn_exp2f(-L2E * gf));
            float ig   = __builtin_amdgcn_rcpf(
                             1.f + __builtin_amdgcn_exp2f(-L2E * gi));
            float o    = __builtin_amdgcn_rcpf(
                             1.f + __builtin_amdgcn_exp2f(-L2E * go));
            float cand = 1.f - 2.f * __builtin_amdgcn_rcpf(
                             __builtin_amdgcn_exp2f(L2E2 * gc) + 1.f);
            c = f * c + ig * cand;
            float tc   = 1.f - 2.f * __builtin_amdgcn_rcpf(
                             __builtin_amdgcn_exp2f(L2E2 * c) + 1.f);
            float hn = o * tc;

            // pair exchange: tail threads 0..7 are lanes 0..7 of wave 0
            float hp = __shfl_xor(hn, 1);         // partner cell's h
            if ((tid & 1) == 0 && t + 1 < T_STEPS) {   // publish FIRST
                unsigned e0 = (__float_as_uint(hn) + 0x80u) >> 8;  // even cell
                unsigned e1 = (__float_as_uint(hp) + 0x80u) >> 8;  // odd cell
                u64 pk = ((u64)(unsigned)(t + 1) << 48)
                       | ((u64)(e0 & 0xFFFFFFu) << 24)
                       | (u64)(e1 & 0xFFFFFFu);
                __hip_atomic_store(
                    slots + ((size_t)((t + 1) & 1) << 10)
                          + blockIdx.x * 4 + (tid >> 1),
                    pk, __ATOMIC_RELAXED, __HIP_MEMORY_SCOPE_AGENT);
            }
            out[(size_t)(blockIdx.x * 8 + tid) * T_STEPS + t] = hn;
        }
        // no third sync needed: hs writes for t+1 happen after this block's
        // compute reads (pre sync B); gdot/c for t+1 written after sync A(t+1)
    }
}

// ---------------------------------------------------------------------------
extern "C" void kernel_launch(void* const* d_in, const int* in_sizes, int n_in,
                              void* d_out, int out_size, void* d_ws, size_t ws_size,
                              hipStream_t stream) {
    const float* x  = (const float*)d_in[0];
    const float* Wf = (const float*)d_in[1];
    const float* bf = (const float*)d_in[2];
    const float* Wi = (const float*)d_in[3];
    const float* bi = (const float*)d_in[4];
    const float* Wc = (const float*)d_in[5];
    const float* bc = (const float*)d_in[6];
    const float* Wo = (const float*)d_in[7];
    const float* bo = (const float*)d_in[8];
    float* out = (float*)d_out;

    // ws layout: Gx fp32 [8192][2048] | pair slots u64 [2][1024]
    const size_t gx_elems = (size_t)R_TOTAL * T_STEPS;
    const size_t need = gx_elems * 4 + 2 * SLOT_PAIRS * 8;
    if (ws_size < need) return;
    float* Gx    = (float*)d_ws;
    u64*   slots = (u64*)(Gx + gx_elems);

    lstm_init_kernel<<<8, 256, 0, stream>>>(slots);

    lstm_gx_kernel<<<2048, 256, 0, stream>>>(Wf, bf, Wi, bi, Wc, bc, Wo, bo,
                                             x, Gx);

    lstm_rec_kernel<<<NBLK, NTHR, 0, stream>>>(Wf, Wi, Wc, Wo, Gx, slots, out);
}

// Round 8
// 5625.211 us; speedup vs baseline: 2.6440x; 1.0382x over previous
//
#include <hip/hip_runtime.h>
#include <math.h>

#define D_IN    1024
#define D_CELL  2048
#define T_STEPS 2048
#define D_Z     3072            // D_IN + D_CELL
#define R_TOTAL (4 * D_CELL)    // 8192 gate rows
#define NBLK    256
#define NTHR    1024

typedef unsigned long long u64;

// ---------------------------------------------------------------------------
// Slot encoding (round-8): ONE u64 per CELL PAIR, packed:
//   [63:56] tag = t & 0xFF (8 bits is safe: a parity slot only ever holds
//           tag t or t-2, distinct mod 256; init zeroes between replays and
//           t starts at 1, so the zero tag can only match at t=256k, by
//           which time the slot has been rewritten ~128 times)
//   [55:28] fp32 bits of h_even, RN-truncated to 28 bits (sign+exp+20 mant)
//   [27: 0] fp32 bits of h_odd,  RN-truncated to 28 bits
// Rel. error <= 2^-21 — restores round-3 accuracy (r7's 24-bit doubled absmax).
// Rationale (rounds 3-7): poll loads hammer the coherence point; cost scales
// with (failed sweeps) x (sectors swept). r7 halved sectors (+11%). r8 cuts
// failed sweeps via backoff. Do NOT: unpack slots across lines (r5: 2x worse),
// start polls before the local tail (r4/r6: 2.3-5x worse), add register-class
// asm (r2: forces scratch spills), or increase polling blocks (r4: 5x worse).
// ---------------------------------------------------------------------------
#define SLOT_PAIRS (D_CELL / 2)          // 1024 pair-slots per parity

// init: zero the pair slots (harness does NOT re-poison ws between timed
// replays; a stale tag from a previous replay would satisfy the poll).
__global__ void lstm_init_kernel(u64* __restrict__ slots) {
    int i = blockIdx.x * 256 + threadIdx.x;
    if (i < 2 * SLOT_PAIRS) slots[i] = 0ull;
}

// ---------------------------------------------------------------------------
// Gx[r][t] = b[r] + sum_k W_g[d][k] * x[k][t]   (k < 1024, input part)
// 1D grid of 2048 blocks, XCD-aware decode: each XCD works on ONE t-half
// (same 4 MiB x tile -> fits its private 4 MiB L2). 256 threads, each
// handles 4 t-columns x 8 rows. W row loads are wave-uniform -> s_load.
// ---------------------------------------------------------------------------
__global__ __launch_bounds__(256) void lstm_gx_kernel(
    const float* __restrict__ Wf, const float* __restrict__ bf,
    const float* __restrict__ Wi, const float* __restrict__ bi,
    const float* __restrict__ Wc, const float* __restrict__ bc,
    const float* __restrict__ Wo, const float* __restrict__ bo,
    const float* __restrict__ x,  float* __restrict__ Gx)
{
    const int bid = blockIdx.x;          // 0..2047
    const int xcd = bid & 7;             // HW round-robin: bid%8 = XCD
    const int loc = bid >> 3;            // 0..255
    const int tx  = xcd >> 2;            // t-half 0/1 (4 XCDs per half)
    const int yb  = (xcd & 3) * 256 + loc;   // row-block 0..1023
    const int tid = threadIdx.x;
    const int t0  = tx * 1024 + tid * 4;
    const int r0  = yb * 8;
    const int g   = r0 >> 11;
    const int d0  = r0 & 2047;
    const float* W = (g == 0) ? Wf : (g == 1) ? Wi : (g == 2) ? Wc : Wo;
    const float* b = (g == 0) ? bf : (g == 1) ? bi : (g == 2) ? bc : bo;

    const float* wr0 = W + (size_t)(d0 + 0) * D_Z;
    const float* wr1 = W + (size_t)(d0 + 1) * D_Z;
    const float* wr2 = W + (size_t)(d0 + 2) * D_Z;
    const float* wr3 = W + (size_t)(d0 + 3) * D_Z;
    const float* wr4 = W + (size_t)(d0 + 4) * D_Z;
    const float* wr5 = W + (size_t)(d0 + 5) * D_Z;
    const float* wr6 = W + (size_t)(d0 + 6) * D_Z;
    const float* wr7 = W + (size_t)(d0 + 7) * D_Z;

    float4 acc[8];
#pragma unroll
    for (int jr = 0; jr < 8; ++jr) acc[jr] = make_float4(0.f, 0.f, 0.f, 0.f);

    for (int k = 0; k < D_IN; k += 4) {
        float4 xa = *(const float4*)(x + (size_t)(k + 0) * T_STEPS + t0);
        float4 xb = *(const float4*)(x + (size_t)(k + 1) * T_STEPS + t0);
        float4 xc = *(const float4*)(x + (size_t)(k + 2) * T_STEPS + t0);
        float4 xd = *(const float4*)(x + (size_t)(k + 3) * T_STEPS + t0);
        const float* wrs[8] = {wr0, wr1, wr2, wr3, wr4, wr5, wr6, wr7};
#pragma unroll
        for (int jr = 0; jr < 8; ++jr) {
            float4 w = *(const float4*)(wrs[jr] + k);   // wave-uniform
            acc[jr].x += w.x * xa.x + w.y * xb.x + w.z * xc.x + w.w * xd.x;
            acc[jr].y += w.x * xa.y + w.y * xb.y + w.z * xc.y + w.w * xd.y;
            acc[jr].z += w.x * xa.z + w.y * xb.z + w.z * xc.z + w.w * xd.z;
            acc[jr].w += w.x * xa.w + w.y * xb.w + w.z * xc.w + w.w * xd.w;
        }
    }

#pragma unroll
    for (int jr = 0; jr < 8; ++jr) {
        float bb = b[d0 + jr];
        float4 o = acc[jr];
        o.x += bb; o.y += bb; o.z += bb; o.w += bb;
        *(float4*)(Gx + (size_t)(r0 + jr) * T_STEPS + t0) = o;
    }
}

// ---------------------------------------------------------------------------
// Persistent recurrence kernel — round-3 skeleton UNCHANGED (256 blocks,
// 16 waves, 2 rows/wave, weight loads before the loop; compiler keeps the
// 64 floats/lane on-chip in AGPRs — do NOT add register-class asm (r2);
// keep sync A + sync B + tid<8 tail (r4/r6: early polling floods fabric)).
// Changes vs round 7: poll backoff (sleep 8 then 2 — cuts failed sweeps
// ~4x, which is coherence-fabric traffic) + tag8/28-bit h encoding.
// ---------------------------------------------------------------------------
__global__ __launch_bounds__(NTHR, 4) void lstm_rec_kernel(
    const float* __restrict__ Wf, const float* __restrict__ Wi,
    const float* __restrict__ Wc, const float* __restrict__ Wo,
    const float* __restrict__ Gx, u64* __restrict__ slots,
    float* __restrict__ out)
{
    __shared__ float hs[D_CELL];     // h_{t-1}, fp32
    __shared__ float gdot[32];       // per-row reduced dots

    const int tid  = threadIdx.x;
    const int w    = tid >> 6;       // wave 0..15
    const int lane = tid & 63;
    const int r0   = 2 * w;          // rows r0, r0+1  (row = cell*4 + gate)

    // ---- load my two weight rows (fp32, stay on-chip in VGPRs/AGPRs) ----
    const int g0 = r0 & 3,        g1 = (r0 + 1) & 3;
    const int cl = r0 >> 2;                       // same cell for both rows
    const int d  = blockIdx.x * 8 + cl;           // global cell
    const float* Wb0 = ((g0 == 0) ? Wf : (g0 == 1) ? Wi : (g0 == 2) ? Wc : Wo)
                       + (size_t)d * D_Z + D_IN;
    const float* Wb1 = ((g1 == 0) ? Wf : (g1 == 1) ? Wi : (g1 == 2) ? Wc : Wo)
                       + (size_t)d * D_Z + D_IN;
    float4 wA[8], wB[8];
#pragma unroll
    for (int j = 0; j < 8; ++j) {
        wA[j] = *(const float4*)(Wb0 + j * 256 + lane * 4);
        wB[j] = *(const float4*)(Wb1 + j * 256 + lane * 4);
    }

    // Gx row base for lanes 0,1 (lane L handles row r0+L)
    const int myrow = r0 + (lane & 1);
    const size_t gxbase = (size_t)((myrow & 3) * D_CELL
                                   + blockIdx.x * 8 + (myrow >> 2)) * T_STEPS;

    float c = 0.f;                   // cell state (tid<8 threads own cell tid)
    const float L2E  = 1.442695041f;     // log2(e)
    const float L2E2 = 2.885390082f;     // 2*log2(e)

    for (int t = 0; t < T_STEPS; ++t) {
        // prefetch Gx early (independent of poll)
        float gx_pref = 0.f;
        if (lane < 2) gx_pref = Gx[gxbase + t];

        // ---- acquire h_{t-1}: ONE packed pair-slot poll, with backoff ----
        if (t == 0) {
            hs[2 * tid]     = 0.f;
            hs[2 * tid + 1] = 0.f;
        } else {
            const u64* bp = slots + ((size_t)(t & 1) << 10) + tid;  // pair tid
            const u64 tg = (u64)(unsigned)(t & 0xFF) << 56;
            u64 s = __hip_atomic_load(bp, __ATOMIC_RELAXED,
                                      __HIP_MEMORY_SCOPE_AGENT);
            if ((s ^ tg) >> 56) {
                __builtin_amdgcn_s_sleep(8);      // dead window: stay off fabric
                for (;;) {
                    s = __hip_atomic_load(bp, __ATOMIC_RELAXED,
                                          __HIP_MEMORY_SCOPE_AGENT);
                    if (((s ^ tg) >> 56) == 0) break;
                    __builtin_amdgcn_s_sleep(2);
                }
            }
            hs[2 * tid]     = __uint_as_float(
                                  ((unsigned)(s >> 28) & 0xFFFFFFFu) << 4);
            hs[2 * tid + 1] = __uint_as_float((unsigned)(s & 0xFFFFFFFu) << 4);
        }
        __syncthreads();                          // sync A: hs ready

        // ---- two gate-row dot slices from on-chip weights ----
        float acc0 = 0.f, acc1 = 0.f;
#pragma unroll
        for (int j = 0; j < 8; ++j) {
            float4 h = *(const float4*)(hs + j * 256 + lane * 4);
            acc0 += wA[j].x * h.x + wA[j].y * h.y + wA[j].z * h.z + wA[j].w * h.w;
            acc1 += wB[j].x * h.x + wB[j].y * h.y + wB[j].z * h.z + wB[j].w * h.w;
        }
        // paired butterfly: even lanes -> row r0 sum, odd lanes -> row r0+1
        float vK = (lane & 1) ? acc1 : acc0;
        float vO = (lane & 1) ? acc0 : acc1;
        float v  = vK + __shfl_xor(vO, 1);
        v += __shfl_xor(v, 2);
        v += __shfl_xor(v, 4);
        v += __shfl_xor(v, 8);
        v += __shfl_xor(v, 16);
        v += __shfl_xor(v, 32);
        if (lane < 2) gdot[r0 + lane] = v + gx_pref;
        __syncthreads();                          // sync B: gdot ready

        // ---- activations: one thread per owned cell (fast exp2/rcp) ----
        if (tid < 8) {
            float gf = gdot[tid * 4 + 0], gi = gdot[tid * 4 + 1];
            float gc = gdot[tid * 4 + 2], go = gdot[tid * 4 + 3];
            float f    = __builtin_amdgcn_rcpf(
                             1.f + __builtin_amdgcn_exp2f(-L2E * gf));
            float ig   = __builtin_amdgcn_rcpf(
                             1.f + __builtin_amdgcn_exp2f(-L2E * gi));
            float o    = __builtin_amdgcn_rcpf(
                             1.f + __builtin_amdgcn_exp2f(-L2E * go));
            float cand = 1.f - 2.f * __builtin_amdgcn_rcpf(
                             __builtin_amdgcn_exp2f(L2E2 * gc) + 1.f);
            c = f * c + ig * cand;
            float tc   = 1.f - 2.f * __builtin_amdgcn_rcpf(
                             __builtin_amdgcn_exp2f(L2E2 * c) + 1.f);
            float hn = o * tc;

            // pair exchange: tail threads 0..7 are lanes 0..7 of wave 0
            float hp = __shfl_xor(hn, 1);         // partner cell's h
            if ((tid & 1) == 0 && t + 1 < T_STEPS) {   // publish FIRST
                unsigned e0 = (__float_as_uint(hn) + 0x8u) >> 4;   // even cell
                unsigned e1 = (__float_as_uint(hp) + 0x8u) >> 4;   // odd cell
                u64 pk = ((u64)(unsigned)((t + 1) & 0xFF) << 56)
                       | ((u64)(e0 & 0xFFFFFFFu) << 28)
                       | (u64)(e1 & 0xFFFFFFFu);
                __hip_atomic_store(
                    slots + ((size_t)((t + 1) & 1) << 10)
                          + blockIdx.x * 4 + (tid >> 1),
                    pk, __ATOMIC_RELAXED, __HIP_MEMORY_SCOPE_AGENT);
            }
            out[(size_t)(blockIdx.x * 8 + tid) * T_STEPS + t] = hn;
        }
        // no third sync needed: hs writes for t+1 happen after this block's
        // compute reads (pre sync B); gdot/c for t+1 written after sync A(t+1)
    }
}

// ---------------------------------------------------------------------------
extern "C" void kernel_launch(void* const* d_in, const int* in_sizes, int n_in,
                              void* d_out, int out_size, void* d_ws, size_t ws_size,
                              hipStream_t stream) {
    const float* x  = (const float*)d_in[0];
    const float* Wf = (const float*)d_in[1];
    const float* bf = (const float*)d_in[2];
    const float* Wi = (const float*)d_in[3];
    const float* bi = (const float*)d_in[4];
    const float* Wc = (const float*)d_in[5];
    const float* bc = (const float*)d_in[6];
    const float* Wo = (const float*)d_in[7];
    const float* bo = (const float*)d_in[8];
    float* out = (float*)d_out;

    // ws layout: Gx fp32 [8192][2048] | pair slots u64 [2][1024]
    const size_t gx_elems = (size_t)R_TOTAL * T_STEPS;
    const size_t need = gx_elems * 4 + 2 * SLOT_PAIRS * 8;
    if (ws_size < need) return;
    float* Gx    = (float*)d_ws;
    u64*   slots = (u64*)(Gx + gx_elems);

    lstm_init_kernel<<<8, 256, 0, stream>>>(slots);

    lstm_gx_kernel<<<2048, 256, 0, stream>>>(Wf, bf, Wi, bi, Wc, bc, Wo, bo,
                                             x, Gx);

    lstm_rec_kernel<<<NBLK, NTHR, 0, stream>>>(Wf, Wi, Wc, Wo, Gx, slots, out);
}